// Round 3
// baseline (2168.198 us; speedup 1.0000x reference)
//
#include <hip/hip_runtime.h>
#include <hip/hip_fp16.h>

// ---------------------------------------------------------------------------
// Bidirectional 5-layer LSTM decoder, B=1024, H=32, T=200, feedback y->x.
// Round 3: R=4 rows per block x S=4 k-split waves.
//   - 256 blocks (1/CU), 4 waves each (1024 waves = 1/SIMD, all SIMDs busy)
//   - each wave loads a quarter of the weight stream and dots it against
//     4 rows -> per-CU weight traffic drops 4x vs round 2.
//   - cross-wave K reduction via LDS partial buffer; wave w finalizes row w.
//   - activations kept f16-packed in LDS as [k-pair][row] so one
//     ds_read_b128 broadcast serves all 4 rows.
// Weight layout (prep kernel, verified round 2): WT[l][d][k2][u][g][2] f16.
// ---------------------------------------------------------------------------

#define T_STEPS 200
#define BATCH 1024

#define W_ELEMS     107520            // f16 packed weights
#define BIAS_OFF_B  215040            // 1280 floats [l][d][u][g]
#define WLIN_OFF_B  220160            // 192 floats [3][64]
#define BLIN_OFF_B  220928            // 3 floats
#define START_OFF_B 220940            // 3 floats

typedef _Float16 h2 __attribute__((ext_vector_type(2)));

__global__ __launch_bounds__(256) void prep_kernel(
    const float* __restrict__ Wih0, const float* __restrict__ Whh0,
    const float* __restrict__ bih0, const float* __restrict__ bhh0,
    const float* __restrict__ Wih,  const float* __restrict__ Whh,
    const float* __restrict__ bih,  const float* __restrict__ bhh,
    const float* __restrict__ Wlin, const float* __restrict__ blin,
    const float* __restrict__ stok, char* __restrict__ ws)
{
    int i = blockIdx.x * 256 + threadIdx.x;
    _Float16* Wo = (_Float16*)ws;
    float* biasf  = (float*)(ws + BIAS_OFF_B);
    float* wlinf  = (float*)(ws + WLIN_OFF_B);
    float* blinf  = (float*)(ws + BLIN_OFF_B);
    float* startf = (float*)(ws + START_OFF_B);

    if (i < W_ELEMS) {
        int l, d, r, Kx;
        if (i < 9216) { l = 0; d = i / 4608; r = i % 4608; Kx = 4; }  // K0 = 4(pad:3+1) + 32
        else {
            int e = i - 9216;
            l = 1 + e / 24576;
            int r2 = e % 24576;
            d = r2 / 12288; r = r2 % 12288; Kx = 64;                   // K = 64 + 32
        }
        int k2 = r >> 8;            // 256 elems per k-pair block (32u * 4g * 2)
        int q  = r & 255;
        int u  = q >> 3;
        int g  = (q >> 1) & 3;
        int p  = q & 1;
        int k  = k2 * 2 + p;
        int gr = g * 32 + u;        // gate row in 4H (torch order i,f,g,o)
        float v = 0.f;
        if (k < Kx) {
            if (l == 0) { if (k < 3) v = Wih0[(d * 128 + gr) * 3 + k]; }
            else        v = Wih[(((l - 1) * 2 + d) * 128 + gr) * 64 + k];
        } else {
            int kh = k - Kx;
            if (l == 0) v = Whh0[(d * 128 + gr) * 32 + kh];
            else        v = Whh[(((l - 1) * 2 + d) * 128 + gr) * 32 + kh];
        }
        Wo[i] = (_Float16)v;
    } else if (i < W_ELEMS + 1280) {
        int b = i - W_ELEMS;                 // [l*2+d][u][g]
        int ld = b / 128; int rem = b % 128;
        int u = rem / 4;  int g = rem % 4;
        int gr = g * 32 + u;
        float v;
        if (ld < 2) v = bih0[ld * 128 + gr] + bhh0[ld * 128 + gr];
        else        v = bih[(ld - 2) * 128 + gr] + bhh[(ld - 2) * 128 + gr];
        biasf[b] = v;
    } else if (i < W_ELEMS + 1280 + 192) {
        wlinf[i - (W_ELEMS + 1280)] = Wlin[i - (W_ELEMS + 1280)];
    } else if (i < W_ELEMS + 1280 + 192 + 3) {
        blinf[i - (W_ELEMS + 1280 + 192)] = blin[i - (W_ELEMS + 1280 + 192)];
    } else if (i < W_ELEMS + 1280 + 192 + 6) {
        startf[i - (W_ELEMS + 1280 + 192 + 3)] = stok[i - (W_ELEMS + 1280 + 192 + 3)];
    }
}

__device__ __forceinline__ float sigm(float x)  { return 1.f / (1.f + __expf(-x)); }
__device__ __forceinline__ float tanhx(float x) { return 2.f * sigm(2.f * x) - 1.f; }
__device__ __forceinline__ h2 as_h2(unsigned v) { return __builtin_bit_cast(h2, v); }

__device__ __forceinline__ float fdot2f(h2 a, h2 b, float c) {
#if __has_builtin(__builtin_amdgcn_fdot2)
    return __builtin_amdgcn_fdot2(a, b, c, false);
#else
    return fmaf((float)a.x, (float)b.x, fmaf((float)a.y, (float)b.y, c));
#endif
}

__device__ __forceinline__ unsigned short f2h_bits(float x) {
    return __builtin_bit_cast(unsigned short, (_Float16)x);
}
__device__ __forceinline__ unsigned packh2(float lo, float hi) {
    return (unsigned)f2h_bits(lo) | ((unsigned)f2h_bits(hi) << 16);
}

#define DOT4R(A, WV, XV)                                \
    A.x = fdot2f(as_h2((WV).x), (XV), A.x);             \
    A.y = fdot2f(as_h2((WV).y), (XV), A.y);             \
    A.z = fdot2f(as_h2((WV).z), (XV), A.z);             \
    A.w = fdot2f(as_h2((WV).w), (XV), A.w);

// dot over this wave's 12-chunk slice of layer l (1..4), for 4 rows at once.
// wbase already includes layer, direction and lane-u offsets.
template<int S>
__device__ __forceinline__ void dot_slice(
    const uint4* __restrict__ wbase, const unsigned* __restrict__ hb,
    int l, int d, float4& a0, float4& a1, float4& a2, float4& a3)
{
    const uint4* wp = wbase + S * 384;          // 12 chunks * 32 uint4
#pragma unroll
    for (int cc = 0; cc < 12; cc++) {
        const int c = S * 12 + cc;              // compile-time after unroll
        uint4 wv = wp[cc * 32];
        int hrow = (c < 32) ? ((l - 1) * 32 + c) : (l * 32 + d * 16 + (c - 32));
        uint4 xv = *(const uint4*)(hb + hrow * 4);
        DOT4R(a0, wv, as_h2(xv.x));
        DOT4R(a1, wv, as_h2(xv.y));
        DOT4R(a2, wv, as_h2(xv.z));
        DOT4R(a3, wv, as_h2(xv.w));
    }
}

__global__ __launch_bounds__(256) void lstm_kernel(
    const char* __restrict__ ws,
    const float* __restrict__ h0,
    const float* __restrict__ c0,
    float* __restrict__ out)
{
    const int tid  = threadIdx.x;
    const int w    = tid >> 6;          // wave id = k-slice id = finalize row
    const int lane = tid & 63;
    const int d    = lane >> 5;
    const int u    = lane & 31;
    const int row  = blockIdx.x * 4 + w;

    // LDS: partial gate sums [s][r][lane], packed activations hbuf[l][j][r],
    // feedback ybuf[chunk][r].
    __shared__ float4  pbuf4[4 * 4 * 64];              // 16 KB
    __shared__ __align__(16) unsigned hbuf[5 * 32 * 4];// 2.5 KB
    __shared__ __align__(16) unsigned ybuf[8];         // 32 B

    const _Float16* W = (const _Float16*)ws;
    const float* biasf  = (const float*)(ws + BIAS_OFF_B);
    const float* wlinf  = (const float*)(ws + WLIN_OFF_B);
    const float* blinf  = (const float*)(ws + BLIN_OFF_B);
    const float* startf = (const float*)(ws + START_OFF_B);

    // cell state: wave w holds c for row w only
    float cs[5];
#pragma unroll
    for (int l = 0; l < 5; l++) {
        int idx = ((2 * l + d) * BATCH + row) * 32 + u;
        cs[l] = c0[idx];
        float hv = h0[idx];
        float hp = __shfl_xor(hv, 1);
        if (!(lane & 1)) hbuf[l * 128 + (lane >> 1) * 4 + w] = packh2(hv, hp);
    }
    float4 bias4[5];
#pragma unroll
    for (int l = 0; l < 5; l++)
        bias4[l] = *(const float4*)(biasf + ((l * 2 + d) * 32 + u) * 4);

    const uint4* wp0_base = (const uint4*)W + d * 576 + u;     // layer 0
    const uint4* wbase[4];
#pragma unroll
    for (int l = 1; l < 5; l++)
        wbase[l - 1] = (const uint4*)W + 1152 + ((l - 1) * 2 + d) * 1536 + u;

    const float wl0 = wlinf[lane], wl1 = wlinf[64 + lane], wl2 = wlinf[128 + lane];
    const float bl0 = blinf[0], bl1 = blinf[1], bl2 = blinf[2];

    // feedback init = start token (same for every row)
    if (lane == 0) {
        float y0 = startf[0], y1 = startf[1], y2 = startf[2];
        ybuf[w]     = packh2(y0, y1);
        ybuf[4 + w] = packh2(y2, 0.f);
    }
    __syncthreads();

    for (int t = 0; t < T_STEPS; t++) {
        // =========== layer 0 dot: 16 h-chunks split 4/wave, wave0 + y-chunks
        float4 a0 = {0,0,0,0}, a1 = {0,0,0,0}, a2 = {0,0,0,0}, a3 = {0,0,0,0};
        {
            const int s4 = w * 4;
#pragma unroll
            for (int cc = 0; cc < 4; cc++) {
                uint4 wv = wp0_base[(2 + s4 + cc) * 32];
                uint4 xv = *(const uint4*)(hbuf + (d * 16 + s4 + cc) * 4);
                DOT4R(a0, wv, as_h2(xv.x));
                DOT4R(a1, wv, as_h2(xv.y));
                DOT4R(a2, wv, as_h2(xv.z));
                DOT4R(a3, wv, as_h2(xv.w));
            }
            if (w == 0) {
                uint4 wv = wp0_base[0];
                uint4 xv = *(const uint4*)&ybuf[0];
                DOT4R(a0, wv, as_h2(xv.x));
                DOT4R(a1, wv, as_h2(xv.y));
                DOT4R(a2, wv, as_h2(xv.z));
                DOT4R(a3, wv, as_h2(xv.w));
                wv = wp0_base[32];
                xv = *(const uint4*)&ybuf[4];
                DOT4R(a0, wv, as_h2(xv.x));
                DOT4R(a1, wv, as_h2(xv.y));
                DOT4R(a2, wv, as_h2(xv.z));
                DOT4R(a3, wv, as_h2(xv.w));
            }
        }
        float hfin;   // wave w's per-lane h of row w after finalize (layer 4 use)
#pragma unroll
        for (int l = 0; l < 5; l++) {
            // write partials for 4 rows
            pbuf4[(w * 4 + 0) * 64 + lane] = a0;
            pbuf4[(w * 4 + 1) * 64 + lane] = a1;
            pbuf4[(w * 4 + 2) * 64 + lane] = a2;
            pbuf4[(w * 4 + 3) * 64 + lane] = a3;
            __syncthreads();
            // finalize row w
            float4 g = bias4[l];
#pragma unroll
            for (int s2 = 0; s2 < 4; s2++) {
                float4 p = pbuf4[(s2 * 4 + w) * 64 + lane];
                g.x += p.x; g.y += p.y; g.z += p.z; g.w += p.w;
            }
            float ii = sigm(g.x), ff = sigm(g.y), gg = tanhx(g.z), oo = sigm(g.w);
            cs[l] = ff * cs[l] + ii * gg;
            float h = oo * tanhx(cs[l]);
            float hp = __shfl_xor(h, 1);
            if (!(lane & 1)) hbuf[l * 128 + (lane >> 1) * 4 + w] = packh2(h, hp);
            hfin = h;
            __syncthreads();
            // next layer dot
            if (l < 4) {
                a0 = {0,0,0,0}; a1 = {0,0,0,0}; a2 = {0,0,0,0}; a3 = {0,0,0,0};
                const int nl = l + 1;
                switch (w) {
                    case 0: dot_slice<0>(wbase[nl - 1], hbuf, nl, d, a0, a1, a2, a3); break;
                    case 1: dot_slice<1>(wbase[nl - 1], hbuf, nl, d, a0, a1, a2, a3); break;
                    case 2: dot_slice<2>(wbase[nl - 1], hbuf, nl, d, a0, a1, a2, a3); break;
                    default: dot_slice<3>(wbase[nl - 1], hbuf, nl, d, a0, a1, a2, a3); break;
                }
            }
        }

        // =========== output linear + tanh + feedback (row w, h in hfin)
        {
            float p0 = hfin * wl0, p1 = hfin * wl1, p2 = hfin * wl2;
#pragma unroll
            for (int off = 32; off >= 1; off >>= 1) {
                p0 += __shfl_xor(p0, off);
                p1 += __shfl_xor(p1, off);
                p2 += __shfl_xor(p2, off);
            }
            float y0 = tanhx(p0 + bl0);
            float y1 = tanhx(p1 + bl1);
            float y2 = tanhx(p2 + bl2);
            if (lane == 0) {
                ybuf[w]     = packh2(y0, y1);
                ybuf[4 + w] = packh2(y2, 0.f);
            }
            if (lane < 3) {
                float yv = (lane == 0) ? y0 : (lane == 1 ? y1 : y2);
                out[(t * BATCH + row) * 3 + lane] = yv;
            }
        }
        __syncthreads();
    }
}

extern "C" void kernel_launch(void* const* d_in, const int* in_sizes, int n_in,
                              void* d_out, int out_size, void* d_ws, size_t ws_size,
                              hipStream_t stream)
{
    const float* h0   = (const float*)d_in[0];
    const float* c0   = (const float*)d_in[1];
    const float* stok = (const float*)d_in[2];
    const float* Wih0 = (const float*)d_in[3];
    const float* Whh0 = (const float*)d_in[4];
    const float* bih0 = (const float*)d_in[5];
    const float* bhh0 = (const float*)d_in[6];
    const float* Wih  = (const float*)d_in[7];
    const float* Whh  = (const float*)d_in[8];
    const float* bih  = (const float*)d_in[9];
    const float* bhh  = (const float*)d_in[10];
    const float* Wlin = (const float*)d_in[11];
    const float* blin = (const float*)d_in[12];

    prep_kernel<<<426, 256, 0, stream>>>(Wih0, Whh0, bih0, bhh0, Wih, Whh,
                                         bih, bhh, Wlin, blin, stok, (char*)d_ws);
    lstm_kernel<<<256, 256, 0, stream>>>((const char*)d_ws, h0, c0,
                                         (float*)d_out);
}

// Round 5
// 1225.239 us; speedup vs baseline: 1.7696x; 1.7696x over previous
//
#include <hip/hip_runtime.h>
#include <hip/hip_fp16.h>

// ---------------------------------------------------------------------------
// Bidirectional 5-layer LSTM decoder, B=1024, H=32, T=200, feedback y->x.
// Round 5 = round 4's byte re-homing + two fixes:
//  (1) NaN root cause: activation LDS stores were unsigned short while loads
//      were unsigned/uint4 -> TBAA let the compiler hoist loads above stores
//      once round 2's barriers were removed. Now ALL activation LDS traffic
//      is 32-bit unsigned (shfl-pack in registers, even lanes store), plus an
//      explicit compiler memory fence after stores. Wave-local LDS is
//      processed in order by HW, so no runtime barrier is needed.
//  (2) Round-2 counters showed L2-latency-bound (VALUBusy 29.6%): streamed
//      layers 3-4 now use a manual double-buffered pipeline (16 uint4 in
//      flight), and the t-loop has NO barriers so the 4 waves drift and
//      overlap LDS-pipe work (layers 1-2) with the L2 stream (layers 3-4).
// Layout: layer0 weights in VGPRs; layers 1-2 in LDS (98.3 KB, preloaded);
// layers 3-4 streamed from L2. Weight layout WT[l][d][k2][u][g][2] f16
// (prep kernel verified rounds 2-4).
// ---------------------------------------------------------------------------

#define T_STEPS 200
#define BATCH 1024

#define W_ELEMS     107520            // f16 packed weights
#define BIAS_OFF_B  215040            // 1280 floats [l][d][u][g]
#define WLIN_OFF_B  220160            // 192 floats [3][64]
#define BLIN_OFF_B  220928            // 3 floats
#define START_OFF_B 220940            // 3 floats

typedef _Float16 h2 __attribute__((ext_vector_type(2)));

__global__ __launch_bounds__(256) void prep_kernel(
    const float* __restrict__ Wih0, const float* __restrict__ Whh0,
    const float* __restrict__ bih0, const float* __restrict__ bhh0,
    const float* __restrict__ Wih,  const float* __restrict__ Whh,
    const float* __restrict__ bih,  const float* __restrict__ bhh,
    const float* __restrict__ Wlin, const float* __restrict__ blin,
    const float* __restrict__ stok, char* __restrict__ ws)
{
    int i = blockIdx.x * 256 + threadIdx.x;
    _Float16* Wo = (_Float16*)ws;
    float* biasf  = (float*)(ws + BIAS_OFF_B);
    float* wlinf  = (float*)(ws + WLIN_OFF_B);
    float* blinf  = (float*)(ws + BLIN_OFF_B);
    float* startf = (float*)(ws + START_OFF_B);

    if (i < W_ELEMS) {
        int l, d, r, Kx;
        if (i < 9216) { l = 0; d = i / 4608; r = i % 4608; Kx = 4; }  // K0 = 4(pad:3+1) + 32
        else {
            int e = i - 9216;
            l = 1 + e / 24576;
            int r2 = e % 24576;
            d = r2 / 12288; r = r2 % 12288; Kx = 64;                   // K = 64 + 32
        }
        int k2 = r >> 8;            // 256 elems per k-pair block (32u * 4g * 2)
        int q  = r & 255;
        int u  = q >> 3;
        int g  = (q >> 1) & 3;
        int p  = q & 1;
        int k  = k2 * 2 + p;
        int gr = g * 32 + u;        // gate row in 4H (torch order i,f,g,o)
        float v = 0.f;
        if (k < Kx) {
            if (l == 0) { if (k < 3) v = Wih0[(d * 128 + gr) * 3 + k]; }
            else        v = Wih[(((l - 1) * 2 + d) * 128 + gr) * 64 + k];
        } else {
            int kh = k - Kx;
            if (l == 0) v = Whh0[(d * 128 + gr) * 32 + kh];
            else        v = Whh[(((l - 1) * 2 + d) * 128 + gr) * 32 + kh];
        }
        Wo[i] = (_Float16)v;
    } else if (i < W_ELEMS + 1280) {
        int b = i - W_ELEMS;                 // [l*2+d][u][g]
        int ld = b / 128; int rem = b % 128;
        int u = rem / 4;  int g = rem % 4;
        int gr = g * 32 + u;
        float v;
        if (ld < 2) v = bih0[ld * 128 + gr] + bhh0[ld * 128 + gr];
        else        v = bih[(ld - 2) * 128 + gr] + bhh[(ld - 2) * 128 + gr];
        biasf[b] = v;
    } else if (i < W_ELEMS + 1280 + 192) {
        wlinf[i - (W_ELEMS + 1280)] = Wlin[i - (W_ELEMS + 1280)];
    } else if (i < W_ELEMS + 1280 + 192 + 3) {
        blinf[i - (W_ELEMS + 1280 + 192)] = blin[i - (W_ELEMS + 1280 + 192)];
    } else if (i < W_ELEMS + 1280 + 192 + 6) {
        startf[i - (W_ELEMS + 1280 + 192 + 3)] = stok[i - (W_ELEMS + 1280 + 192 + 3)];
    }
}

__device__ __forceinline__ float sigm(float x)  { return 1.f / (1.f + __expf(-x)); }
__device__ __forceinline__ float tanhx(float x) { return 2.f * sigm(2.f * x) - 1.f; }
__device__ __forceinline__ h2 as_h2(unsigned v) { return __builtin_bit_cast(h2, v); }

__device__ __forceinline__ float fdot2f(h2 a, h2 b, float c) {
#if __has_builtin(__builtin_amdgcn_fdot2)
    return __builtin_amdgcn_fdot2(a, b, c, false);
#else
    return fmaf((float)a.x, (float)b.x, fmaf((float)a.y, (float)b.y, c));
#endif
}

__device__ __forceinline__ unsigned short f2h_bits(float x) {
    return __builtin_bit_cast(unsigned short, (_Float16)x);
}
__device__ __forceinline__ unsigned packh2(float lo, float hi) {
    return (unsigned)f2h_bits(lo) | ((unsigned)f2h_bits(hi) << 16);
}

#define DOT4(WV, XV)                                  \
    acc.x = fdot2f(as_h2((WV).x), (XV), acc.x);       \
    acc.y = fdot2f(as_h2((WV).y), (XV), acc.y);       \
    acc.z = fdot2f(as_h2((WV).z), (XV), acc.z);       \
    acc.w = fdot2f(as_h2((WV).w), (XV), acc.w);

// 48-chunk dot (32 x-chunks + 16 h-chunks) with a double-buffered pipeline:
// two groups of 8 uint4 in flight. Works for both LDS and global pointers.
template<typename WP>
__device__ __forceinline__ void dot48_pipe(WP wp, const unsigned* xp,
                                           const unsigned* hp, float4& acc)
{
    uint4 buf[8];
#pragma unroll
    for (int j = 0; j < 8; j++) buf[j] = wp[j * 32];
#pragma unroll
    for (int g2 = 0; g2 < 6; g2++) {
        uint4 nxt[8];
        if (g2 < 5) {
#pragma unroll
            for (int j = 0; j < 8; j++) nxt[j] = wp[((g2 + 1) * 8 + j) * 32];
        }
#pragma unroll
        for (int j = 0; j < 8; j++) {
            const int c = g2 * 8 + j;
            h2 av = as_h2((c < 32) ? xp[c] : hp[c - 32]);
            uint4 wv = buf[j];
            DOT4(wv, av);
        }
        if (g2 < 5) {
#pragma unroll
            for (int j = 0; j < 8; j++) buf[j] = nxt[j];
        }
    }
}

extern __shared__ uint4 smem[];   // [0,6144): L1+L2 weights; then activations

__global__ __launch_bounds__(256, 1) void lstm_kernel(
    const char* __restrict__ ws,
    const float* __restrict__ h0,
    const float* __restrict__ c0,
    float* __restrict__ out)
{
    const int tid  = threadIdx.x;
    const int w    = tid >> 6;          // wave in block (0..3) = row slot
    const int lane = tid & 63;
    const int d    = lane >> 5;
    const int u    = lane & 31;
    const int row  = blockIdx.x * 4 + w;

    unsigned* abuf = (unsigned*)(smem + 6144);
    unsigned* xbh  = abuf + w * 32;         // layer input, 64 f16 as 32 words
    unsigned* hbh  = abuf + 128 + w * 32;   // recurrent h,  64 f16 as 32 words

    const uint4* gw = (const uint4*)ws;     // f16 weights viewed as uint4

    // ---- cooperative preload of layers 1-2 weights into LDS (once) ----
    for (int i = tid; i < 6144; i += 256) smem[i] = gw[1152 + i];

    const float* biasf  = (const float*)(ws + BIAS_OFF_B);
    const float* wlinf  = (const float*)(ws + WLIN_OFF_B);
    const float* blinf  = (const float*)(ws + BLIN_OFF_B);
    const float* startf = (const float*)(ws + START_OFF_B);

    // ---- layer-0 weights into registers (18 uint4/lane) ----
    const uint4* wp0_base = gw + d * 576 + u;
    uint4 w0r[18];
#pragma unroll
    for (int j = 0; j < 18; j++) w0r[j] = wp0_base[j * 32];

    float hs[5], cs[5];
#pragma unroll
    for (int l = 0; l < 5; l++) {
        int idx = ((2 * l + d) * BATCH + row) * 32 + u;
        hs[l] = h0[idx];
        cs[l] = c0[idx];
    }
    float4 bias4[5];
#pragma unroll
    for (int l = 0; l < 5; l++)
        bias4[l] = *(const float4*)(biasf + ((l * 2 + d) * 32 + u) * 4);

    const float wl0 = wlinf[lane], wl1 = wlinf[64 + lane], wl2 = wlinf[128 + lane];
    const float bl0 = blinf[0], bl1 = blinf[1], bl2 = blinf[2];
    float y0 = startf[0], y1 = startf[1], y2 = startf[2];

    __syncthreads();    // preload fence (only barrier in the kernel)

    // packed store of a per-lane value into a 32-word/wave LDS buffer:
    // even lanes store (own, lane+1) as one unsigned word. Type-consistent
    // with all unsigned loads; asm fence stops compiler reordering.
#define STORE_PACKED(BUF, V)                                   \
    {                                                          \
        float _p = __shfl_xor((V), 1);                         \
        if (!(lane & 1)) (BUF)[lane >> 1] = packh2((V), _p);   \
    }

    for (int t = 0; t < T_STEPS; t++) {
        // ----- layer 0: weights in registers -----
        STORE_PACKED(hbh, hs[0]);
        __asm__ volatile("" ::: "memory");
        {
            float4 acc = bias4[0];
            h2 y01; y01.x = (_Float16)y0; y01.y = (_Float16)y1;
            h2 y2p; y2p.x = (_Float16)y2; y2p.y = (_Float16)0.f;
            DOT4(w0r[0], y01);
            DOT4(w0r[1], y2p);
            const unsigned* hp = hbh + d * 16;
#pragma unroll
            for (int k2 = 0; k2 < 16; k2++) {
                h2 hx = as_h2(hp[k2]);
                DOT4(w0r[2 + k2], hx);
            }
            float ii = sigm(acc.x), ff = sigm(acc.y), gg = tanhx(acc.z), oo = sigm(acc.w);
            cs[0] = ff * cs[0] + ii * gg;
            hs[0] = oo * tanhx(cs[0]);
        }

        // ----- layers 1-2: weights in LDS -----
#pragma unroll
        for (int l = 1; l <= 2; l++) {
            STORE_PACKED(xbh, hs[l - 1]);
            STORE_PACKED(hbh, hs[l]);
            __asm__ volatile("" ::: "memory");
            float4 acc = bias4[l];
            dot48_pipe((const uint4*)&smem[((l - 1) * 2 + d) * 1536 + u],
                       xbh, hbh + d * 16, acc);
            float ii = sigm(acc.x), ff = sigm(acc.y), gg = tanhx(acc.z), oo = sigm(acc.w);
            cs[l] = ff * cs[l] + ii * gg;
            hs[l] = oo * tanhx(cs[l]);
        }

        // ----- layers 3-4: weights streamed from global (L2-resident) -----
#pragma unroll
        for (int l = 3; l <= 4; l++) {
            STORE_PACKED(xbh, hs[l - 1]);
            STORE_PACKED(hbh, hs[l]);
            __asm__ volatile("" ::: "memory");
            float4 acc = bias4[l];
            dot48_pipe(gw + 1152 + ((l - 1) * 2 + d) * 1536 + u,
                       xbh, hbh + d * 16, acc);
            float ii = sigm(acc.x), ff = sigm(acc.y), gg = tanhx(acc.z), oo = sigm(acc.w);
            cs[l] = ff * cs[l] + ii * gg;
            hs[l] = oo * tanhx(cs[l]);
        }

        // ----- output linear + tanh + feedback (concat = hs[4] per lane) -----
        {
            float v = hs[4];
            float p0 = v * wl0, p1 = v * wl1, p2 = v * wl2;
#pragma unroll
            for (int off = 32; off >= 1; off >>= 1) {
                p0 += __shfl_xor(p0, off);
                p1 += __shfl_xor(p1, off);
                p2 += __shfl_xor(p2, off);
            }
            y0 = tanhx(p0 + bl0);
            y1 = tanhx(p1 + bl1);
            y2 = tanhx(p2 + bl2);
            if (lane < 3) {
                float yv = (lane == 0) ? y0 : (lane == 1 ? y1 : y2);
                out[(t * BATCH + row) * 3 + lane] = yv;
            }
        }
    }
#undef STORE_PACKED
}

extern "C" void kernel_launch(void* const* d_in, const int* in_sizes, int n_in,
                              void* d_out, int out_size, void* d_ws, size_t ws_size,
                              hipStream_t stream)
{
    const float* h0   = (const float*)d_in[0];
    const float* c0   = (const float*)d_in[1];
    const float* stok = (const float*)d_in[2];
    const float* Wih0 = (const float*)d_in[3];
    const float* Whh0 = (const float*)d_in[4];
    const float* bih0 = (const float*)d_in[5];
    const float* bhh0 = (const float*)d_in[6];
    const float* Wih  = (const float*)d_in[7];
    const float* Whh  = (const float*)d_in[8];
    const float* bih  = (const float*)d_in[9];
    const float* bhh  = (const float*)d_in[10];
    const float* Wlin = (const float*)d_in[11];
    const float* blin = (const float*)d_in[12];

    prep_kernel<<<426, 256, 0, stream>>>(Wih0, Whh0, bih0, bhh0, Wih, Whh,
                                         bih, bhh, Wlin, blin, stok, (char*)d_ws);

    // L1+L2 weights (98304 B) + activation buffers (1024 B) of dynamic LDS
    const int dyn_lds = 6144 * 16 + 1024;
    (void)hipFuncSetAttribute((const void*)lstm_kernel,
                              hipFuncAttributeMaxDynamicSharedMemorySize, dyn_lds);
    lstm_kernel<<<256, 256, dyn_lds, stream>>>((const char*)d_ws, h0, c0,
                                               (float*)d_out);
}